// Round 12
// baseline (538.706 us; speedup 1.0000x reference)
//
#include <hip/hip_runtime.h>
#include <math.h>

#define NSEQ 2048
#define NPOS 4095   // 2*NSEQ-1
#define NH   8
#define LOG2E 1.4426950408889634f

typedef _Float16 f16;
typedef f16 f16x8 __attribute__((ext_vector_type(8)));
typedef f16 f16x4 __attribute__((ext_vector_type(4)));
typedef float f32x4 __attribute__((ext_vector_type(4)));

#define MFMA16(a,b,c) __builtin_amdgcn_mfma_f32_16x16x32_f16(a,b,c,0,0,0)
// swizzled LDS byte offset: row stride 128B, 16B-granule XOR on (row&7)
#define LSWZ(row, col) (((row) << 7) + ((((col) << 1)) ^ (((row) & 7) << 4)))

__device__ __forceinline__ f16x8 cvt8(float4 a, float4 b) {
  f16x8 r = {(f16)a.x, (f16)a.y, (f16)a.z, (f16)a.w,
             (f16)b.x, (f16)b.y, (f16)b.z, (f16)b.w};
  return r;
}

// ---------------- positional embedding pos[NPOS][192], one lane per (t,f) ----
__global__ __launch_bounds__(256) void pos_embed_k(float* __restrict__ pos) {
  int t = blockIdx.x * 8 + (threadIdx.x >> 5);
  int f = threadIdx.x & 31;
  if (t >= NPOS) return;
  float dist = (float)(t - (NSEQ - 1));
  float ad = fabsf(dist);
  float sgn = (dist > 0.f) ? 1.f : ((dist < 0.f) ? -1.f : 0.f);
  double mean = 64.0 * (double)(f + 1);       // linspace(64,2048,32)
  double conc = (mean / 32.0) * (mean / 32.0);
  double rate = mean / 1024.0;
  double p = 0.0;
  if (ad > 0.f) {
    double lu = (conc - 1.0) * log((double)ad) - rate * (double)ad;
    double ln = lgamma(conc) - conc * log(rate);
    p = exp(lu - ln);
  }
  float pf = (float)p + 1e-8f;
  float gmax = pf;
  #pragma unroll
  for (int mk = 1; mk <= 16; mk <<= 1) gmax = fmaxf(gmax, __shfl_xor(gmax, mk));
  float fg = pf / gmax;
  float hl = exp2f(3.f + 8.f * (float)f * (1.f / 31.f));
  float fe = exp2f(-ad / hl);
  float cw = exp2f((float)(f + 1)) - 1.f;
  float fc = (cw > ad) ? 1.f : 0.f;
  float* row = pos + (size_t)t * 192;
  row[f]       = fe;       row[32 + f]  = fc;       row[64 + f]  = fg;
  row[96 + f]  = sgn * fe; row[128 + f] = sgn * fc; row[160 + f] = sgn * fg;
}

// ---------------- relq = pos @ Wrel -> f16 [h][NPOS][64], scaled by log2e ---
__global__ __launch_bounds__(256) void relq_k(
    const float* __restrict__ A, const float* __restrict__ W, f16* __restrict__ relq)
{
  __shared__ f16 As[64][56];
  __shared__ f16 Bs[64][56];
  int tid = threadIdx.x, w = tid >> 6, lane = tid & 63, lr = lane >> 4, lc = lane & 15;
  int m0 = blockIdx.y * 64, n0 = blockIdx.x * 64;
  int ar = tid >> 2, ac = (tid & 3) * 8;
  int bk = tid >> 3, bn = (tid & 7) * 8;
  f32x4 acc[4] = {};
  for (int k0 = 0; k0 < 192; k0 += 32) {
    float4 a0 = make_float4(0.f,0.f,0.f,0.f), a1 = a0;
    if (m0 + ar < NPOS) {
      const float* ap = &A[(size_t)(m0 + ar) * 192 + k0 + ac];
      a0 = *(const float4*)ap; a1 = *(const float4*)(ap + 4);
    }
    *(f16x8*)&As[ar][ac] = cvt8(a0, a1);
    const float* bp = &W[(size_t)(k0 + bk) * 512 + n0 + bn];
    float4 b0 = *(const float4*)bp, b1 = *(const float4*)(bp + 4);
    f16 bv[8] = {(f16)b0.x,(f16)b0.y,(f16)b0.z,(f16)b0.w,(f16)b1.x,(f16)b1.y,(f16)b1.z,(f16)b1.w};
    #pragma unroll
    for (int tt = 0; tt < 8; tt++) { int t = (tt + bk) & 7; Bs[bn + t][bk] = bv[t]; }
    __syncthreads();
    f16x8 af = *(const f16x8*)&As[16*w + lc][8*lr];
    #pragma unroll
    for (int nt = 0; nt < 4; nt++) {
      f16x8 bf = *(const f16x8*)&Bs[16*nt + lc][8*lr];
      acc[nt] = MFMA16(af, bf, acc[nt]);
    }
    __syncthreads();
  }
  #pragma unroll
  for (int nt = 0; nt < 4; nt++)
    #pragma unroll
    for (int r = 0; r < 4; r++) {
      int m = m0 + 16*w + 4*lr + r;
      if (m >= NPOS) continue;
      int nn = n0 + 16*nt + lc;
      relq[((size_t)(nn >> 6) * NPOS + m) * 64 + (nn & 63)] = (f16)(acc[nt][r] * LOG2E);
    }
}

// ---------------- input projections (64x64 tile): A[4096,KD] x (W1|W2) -----
// first half  -> O1 head-split; SC1? (*0.125+rpb) : (*log2e)  [kb vs q]
// second half -> O2t TRANSPOSED [bh][d][2048]
template<int KD, bool SC1>
__global__ __launch_bounds__(256) void projx_k(
    const float* __restrict__ A, const float* __restrict__ W1, const float* __restrict__ W2,
    f16* __restrict__ O1, f16* __restrict__ O2t, const float* __restrict__ rpb)
{
  __shared__ f16 As[64][56];
  __shared__ f16 Bs[64][56];
  int tid = threadIdx.x, w = tid >> 6, lane = tid & 63, lr = lane >> 4, lc = lane & 15;
  int m0 = blockIdx.y * 64, n0g = blockIdx.x * 64;
  bool first = (n0g < 512);
  const float* W = first ? W1 : W2;
  int n0 = n0g & 511;
  int ar = tid >> 2, ac = (tid & 3) * 8;
  int bk = tid >> 3, bn = (tid & 7) * 8;
  f32x4 acc[4] = {};
  for (int k0 = 0; k0 < KD; k0 += 32) {
    const float* ap = &A[(size_t)(m0 + ar) * KD + k0 + ac];
    *(f16x8*)&As[ar][ac] = cvt8(*(const float4*)ap, *(const float4*)(ap + 4));
    const float* bp = &W[(size_t)(k0 + bk) * 512 + n0 + bn];
    float4 b0 = *(const float4*)bp, b1 = *(const float4*)(bp + 4);
    f16 bv[8] = {(f16)b0.x,(f16)b0.y,(f16)b0.z,(f16)b0.w,(f16)b1.x,(f16)b1.y,(f16)b1.z,(f16)b1.w};
    #pragma unroll
    for (int tt = 0; tt < 8; tt++) { int t = (tt + bk) & 7; Bs[bn + t][bk] = bv[t]; }
    __syncthreads();
    f16x8 af = *(const f16x8*)&As[16*w + lc][8*lr];
    #pragma unroll
    for (int nt = 0; nt < 4; nt++) {
      f16x8 bf = *(const f16x8*)&Bs[16*nt + lc][8*lr];
      acc[nt] = MFMA16(af, bf, acc[nt]);
    }
    __syncthreads();
  }
  if (first) {
    #pragma unroll
    for (int nt = 0; nt < 4; nt++)
      #pragma unroll
      for (int r = 0; r < 4; r++) {
        int m = m0 + 16*w + 4*lr + r;
        int nn = n0 + 16*nt + lc;
        float vv = acc[nt][r];
        if (SC1) vv = vv * 0.125f + rpb[nn];
        else     vv = vv * LOG2E;
        O1[(((size_t)((m >> 11) * NH + (nn >> 6))) * NSEQ + (m & (NSEQ - 1))) * 64 + (nn & 63)] = (f16)vv;
      }
  } else {
    int mb = m0 + 16*w + 4*lr;
    #pragma unroll
    for (int nt = 0; nt < 4; nt++) {
      int nn = n0 + 16*nt + lc;
      f16x4 pk = {(f16)acc[nt][0], (f16)acc[nt][1], (f16)acc[nt][2], (f16)acc[nt][3]};
      *(f16x4*)&O2t[(((size_t)((mb >> 11) * NH + (nn >> 6))) * 64 + (nn & 63)) * NSEQ + (mb & (NSEQ - 1))] = pk;
    }
  }
}

// ---------------- fused output projections (64x64 tile) ----------------
__global__ __launch_bounds__(256) void outproj_k(
    const f16* __restrict__ o1, const f16* __restrict__ o2,
    const float* __restrict__ Wo1, const float* __restrict__ Wo2,
    const float* __restrict__ bo1, const float* __restrict__ bo2,
    float* __restrict__ out)
{
  __shared__ f16 As[64][56];
  __shared__ f16 Bs[64][56];
  int by = blockIdx.y;
  bool first = (by < 64);
  const f16* A = first ? o1 : o2;
  const float* W = first ? Wo1 : Wo2;
  const float* bias = first ? bo1 : bo2;
  float* O = out + (first ? 0 : (size_t)4096 * 1024);
  int tid = threadIdx.x, w = tid >> 6, lane = tid & 63, lr = lane >> 4, lc = lane & 15;
  int m0 = (by & 63) * 64, n0 = blockIdx.x * 64;
  int ar = tid >> 2, ac = (tid & 3) * 8;
  int bk = tid >> 3, bn = (tid & 7) * 8;
  f32x4 acc[4] = {};
  for (int k0 = 0; k0 < 512; k0 += 32) {
    *(f16x8*)&As[ar][ac] = *(const f16x8*)&A[(size_t)(m0 + ar) * 512 + k0 + ac];
    const float* bp = &W[(size_t)(k0 + bk) * 1024 + n0 + bn];
    float4 b0 = *(const float4*)bp, b1 = *(const float4*)(bp + 4);
    f16 bv[8] = {(f16)b0.x,(f16)b0.y,(f16)b0.z,(f16)b0.w,(f16)b1.x,(f16)b1.y,(f16)b1.z,(f16)b1.w};
    #pragma unroll
    for (int tt = 0; tt < 8; tt++) { int t = (tt + bk) & 7; Bs[bn + t][bk] = bv[t]; }
    __syncthreads();
    f16x8 af = *(const f16x8*)&As[16*w + lc][8*lr];
    #pragma unroll
    for (int nt = 0; nt < 4; nt++) {
      f16x8 bf = *(const f16x8*)&Bs[16*nt + lc][8*lr];
      acc[nt] = MFMA16(af, bf, acc[nt]);
    }
    __syncthreads();
  }
  #pragma unroll
  for (int nt = 0; nt < 4; nt++)
    #pragma unroll
    for (int r = 0; r < 4; r++) {
      int m = m0 + 16*w + 4*lr + r;
      int n = n0 + 16*nt + lc;
      O[(size_t)m * 1024 + n] = acc[nt][r] + bias[n];
    }
}

// ---------------- fused logits + online softmax + out1 PV (split-j) --------
// All logits in log2 domain (q, relq pre-scaled by log2e). Block handles
// jtcnt j-tiles starting at jt0 = split*jtcnt. Outputs per split:
//  attnT[j][i] = 2^(l - m_run_jt), mrun_t[z][jt][i], stats[z*nsplit+split][i]
//  = (m_fin, s), o1part[(z*nsplit+split)][i][d] (f32, 2^m_fin-scaled).
// LDS 40960B, stride-64 XOR-swizzled: QG(Q/G2)@0, KB(+Pw)@8192, R0@16384,
// R1@24576, VS@32768.
__global__ __launch_bounds__(256, 4) void attn_k(
    const f16* __restrict__ q, const f16* __restrict__ kb,
    const f16* __restrict__ relq, const f16* __restrict__ v2t,
    f16* __restrict__ attnT, float* __restrict__ mrun_t,
    float2* __restrict__ stats, float* __restrict__ o1part,
    int bh0, int nsplit, int jtcnt)
{
  __shared__ char smem[40960];
  char* QG = smem;
  char* KB = smem + 8192;
  char* R0 = smem + 16384;
  char* R1 = smem + 24576;
  char* VS = smem + 32768;
  int z = blockIdx.z, bh = bh0 + z, h = bh & 7;
  int i0 = blockIdx.x * 64;
  int split = blockIdx.y, jt0 = split * jtcnt;
  int tid = threadIdx.x, w = tid >> 6, lane = tid & 63;
  int lr = lane >> 4, lc = lane & 15;
  char* PW = KB + w * 2048;          // per-wave [16] swizzled rows
  int base0 = i0 + 1984;             // (NSEQ-1) + i0 - 63
  int row = tid >> 2, c0 = (tid & 3) * 16;

  {
    const f16* qp = q + ((size_t)bh * NSEQ + i0 + row) * 64 + c0;
    *(f16x8*)(QG + LSWZ(row, c0))     = *(const f16x8*)qp;
    *(f16x8*)(QG + LSWZ(row, c0 + 8)) = *(const f16x8*)(qp + 8);
    // prologue: panel jt0-1 -> slot 1 (jt0 even)
    const f16* rp = relq + ((size_t)h * NPOS + base0 + 64 - 64*jt0 + row) * 64 + c0;
    *(f16x8*)(R1 + LSWZ(row, c0))     = *(const f16x8*)rp;
    *(f16x8*)(R1 + LSWZ(row, c0 + 8)) = *(const f16x8*)(rp + 8);
  }
  __syncthreads();
  f16x8 qa0 = *(const f16x8*)(QG + LSWZ(16*w + lc, 8*lr));
  f16x8 qa1 = *(const f16x8*)(QG + LSWZ(16*w + lc, 32 + 8*lr));

  // tile-jt0 prefetch registers
  const f16* kpb  = kb  + ((size_t)bh * NSEQ + jt0 * 64 + row) * 64 + c0;
  const f16* vpb  = v2t + ((size_t)bh * 64 + row) * NSEQ + jt0 * 64 + c0;
  const f16* rpb0 = relq + ((size_t)h * NPOS + base0 - 64*jt0 + row) * 64 + c0;
  f16x8 skb0 = *(const f16x8*)kpb,  skb1 = *(const f16x8*)(kpb + 8);
  f16x8 sv0  = *(const f16x8*)vpb,  sv1  = *(const f16x8*)(vpb + 8);
  f16x8 sr0  = *(const f16x8*)rpb0, sr1  = *(const f16x8*)(rpb0 + 8);

  float m_run[4], ssum[4], mreg[4] = {};
  f32x4 o1a[4] = {};
  #pragma unroll
  for (int r = 0; r < 4; r++) { m_run[r] = -1e30f; ssum[r] = 0.f; }

  for (int jt = jt0; jt < jt0 + jtcnt; jt++) {
    int j0 = jt * 64;
    char* RsA = (jt & 1) ? R1 : R0;   // panel jt: n in [0,64)
    char* RsB = (jt & 1) ? R0 : R1;   // panel jt-1: n in [64,128)
    *(f16x8*)(KB + LSWZ(row, c0))      = skb0;  *(f16x8*)(KB + LSWZ(row, c0 + 8))  = skb1;
    *(f16x8*)(VS + LSWZ(row, c0))      = sv0;   *(f16x8*)(VS + LSWZ(row, c0 + 8))  = sv1;
    *(f16x8*)(RsA + LSWZ(row, c0))     = sr0;   *(f16x8*)(RsA + LSWZ(row, c0 + 8)) = sr1;
    __syncthreads();   // s1: staging visible
    f32x4 cacc[4];
    f16x8 ka0 = {}, ka1 = {};
    __builtin_amdgcn_s_setprio(1);
    #pragma unroll
    for (int y = 0; y < 4; y++) {
      f16x8 b0 = *(const f16x8*)(KB + LSWZ(16*y + lc, 8*lr));
      f16x8 b1 = *(const f16x8*)(KB + LSWZ(16*y + lc, 32 + 8*lr));
      f32x4 t = {};
      t = MFMA16(qa0, b0, t);
      t = MFMA16(qa1, b1, t);
      cacc[y] = t;
      if (y == w) { ka0 = b0; ka1 = b1; }
    }
    __builtin_amdgcn_s_setprio(0);
    // G blocks: only g in [3-w, 7-w] contribute
    #pragma unroll
    for (int gg = 0; gg < 5; gg++) {
      int g = 3 - w + gg;
      char* Rg = (g < 4) ? RsA : RsB;
      int grow = 16 * (g & 3) + lc;
      f32x4 ga = {};
      ga = MFMA16(ka0, *(const f16x8*)(Rg + LSWZ(grow, 8*lr)), ga);
      ga = MFMA16(ka1, *(const f16x8*)(Rg + LSWZ(grow, 32 + 8*lr)), ga);
      int jj = 16*w + 4*lr;
      #pragma unroll
      for (int r = 0; r < 4; r++) {
        int ii = 16*g + lc + jj + r - 63;   // i = n + j - 63
        if ((unsigned)ii < 64u) *(f16*)(QG + LSWZ(jj + r, ii)) = (f16)ga[r];
      }
    }
    // prefetch next tile into registers (hides under softmax+PV)
    {
      int jn = (jt < jt0 + jtcnt - 1) ? jt + 1 : jt;
      const f16* kpn = kb  + ((size_t)bh * NSEQ + jn * 64 + row) * 64 + c0;
      const f16* vpn = v2t + ((size_t)bh * 64 + row) * NSEQ + jn * 64 + c0;
      const f16* rpn = relq + ((size_t)h * NPOS + base0 - 64 * jn + row) * 64 + c0;
      skb0 = *(const f16x8*)kpn;  skb1 = *(const f16x8*)(kpn + 8);
      sv0  = *(const f16x8*)vpn;  sv1  = *(const f16x8*)(vpn + 8);
      sr0  = *(const f16x8*)rpn;  sr1  = *(const f16x8*)(rpn + 8);
    }
    __syncthreads();   // s2: G2 complete; KB frag reads done -> Pw overlay safe
    float l[4][4];
    #pragma unroll
    for (int y = 0; y < 4; y++) {
      f16x4 gv = *(const f16x4*)(QG + LSWZ(16*y + lc, 16*w + 4*lr));
      #pragma unroll
      for (int r = 0; r < 4; r++) l[y][r] = cacc[y][r] + (float)gv[r];
    }
    float pvr[4][4];   // [r][y]
    #pragma unroll
    for (int r = 0; r < 4; r++) {
      float tm = fmaxf(fmaxf(l[0][r], l[1][r]), fmaxf(l[2][r], l[3][r]));
      #pragma unroll
      for (int mk = 1; mk <= 8; mk <<= 1) tm = fmaxf(tm, __shfl_xor(tm, mk));
      if (tm > m_run[r]) {
        float sc = exp2f(m_run[r] - tm);
        ssum[r] *= sc;
        #pragma unroll
        for (int nt = 0; nt < 4; nt++) o1a[nt][r] *= sc;
        m_run[r] = tm;
      }
      float mnew = m_run[r];
      float ps = 0.f;
      #pragma unroll
      for (int y = 0; y < 4; y++) {
        float p = exp2f(l[y][r] - mnew);
        ps += p;
        pvr[r][y] = p;
        *(f16*)(PW + LSWZ(4*lr + r, 16*y + lc)) = (f16)p;
      }
      ssum[r] += ps;
      if (lc == jt - jt0) mreg[r] = mnew;   // lane lc owns tile jt0+lc
    }
    // transposed P store, direct from registers: attnT[j][i]
    #pragma unroll
    for (int y = 0; y < 4; y++) {
      f16x4 pk = {(f16)pvr[0][y], (f16)pvr[1][y], (f16)pvr[2][y], (f16)pvr[3][y]};
      *(f16x4*)&attnT[((size_t)z * NSEQ + j0 + 16*y + lc) * NSEQ + i0 + 16*w + 4*lr] = pk;
    }
    // out1 PV (Pw per-wave, lgkmcnt-ordered)
    {
      f16x8 pa0 = *(const f16x8*)(PW + LSWZ(lc, 8*lr));
      f16x8 pa1 = *(const f16x8*)(PW + LSWZ(lc, 32 + 8*lr));
      __builtin_amdgcn_s_setprio(1);
      #pragma unroll
      for (int nt = 0; nt < 4; nt++) {
        f16x8 vf0 = *(const f16x8*)(VS + LSWZ(16*nt + lc, 8*lr));
        f16x8 vf1 = *(const f16x8*)(VS + LSWZ(16*nt + lc, 32 + 8*lr));
        o1a[nt] = MFMA16(pa0, vf0, o1a[nt]);
        o1a[nt] = MFMA16(pa1, vf1, o1a[nt]);
      }
      __builtin_amdgcn_s_setprio(0);
    }
    __syncthreads();   // s3: all LDS reads done -> restage ok
  }
  // epilogue: per-row s reduce; write mrun_t / stats / o1part
  #pragma unroll
  for (int r = 0; r < 4; r++) {
    float s = ssum[r];
    #pragma unroll
    for (int mk = 1; mk <= 8; mk <<= 1) s += __shfl_xor(s, mk);
    int il = 16*w + 4*lr + r;
    if (lc < jtcnt)
      mrun_t[((size_t)z * 32 + jt0 + lc) * NSEQ + i0 + il] = mreg[r];
    if (lc == 0) {
      float2 st; st.x = m_run[r]; st.y = s;
      stats[((size_t)z * nsplit + split) * NSEQ + i0 + il] = st;
    }
  }
  #pragma unroll
  for (int nt = 0; nt < 4; nt++)
    #pragma unroll
    for (int r = 0; r < 4; r++) {
      int il = 16*w + 4*lr + r;
      o1part[(((size_t)z * nsplit + split) * NSEQ + i0 + il) * 64 + 16*nt + lc] = o1a[nt][r];
    }
}

// ---------------- combine: merge splits -> o1acc + finstats(mf, 1/s) -------
__global__ __launch_bounds__(256) void combine_k(
    const float* __restrict__ o1part, const float2* __restrict__ stats,
    f16* __restrict__ o1acc, float2* __restrict__ finstats,
    int bh0, int nsplit)
{
  int rid = blockIdx.x * 4 + (threadIdx.x >> 6);
  int d = threadIdx.x & 63;
  int z = rid >> 11, i = rid & 2047;
  int bh = bh0 + z, b = bh >> 3, h = bh & 7;
  float mf = -1e30f;
  #pragma unroll 2
  for (int sp = 0; sp < nsplit; sp++)
    mf = fmaxf(mf, stats[((size_t)z * nsplit + sp) * NSEQ + i].x);
  float s = 0.f, acc = 0.f;
  #pragma unroll 2
  for (int sp = 0; sp < nsplit; sp++) {
    float2 st = stats[((size_t)z * nsplit + sp) * NSEQ + i];
    float f = exp2f(st.x - mf);
    s += st.y * f;
    acc += o1part[(((size_t)z * nsplit + sp) * NSEQ + i) * 64 + d] * f;
  }
  float invs = 1.f / s;
  if (d == 0) { float2 fs; fs.x = mf; fs.y = invs; finstats[(size_t)z * NSEQ + i] = fs; }
  o1acc[((size_t)b * NSEQ + i) * 512 + h * 64 + d] = (f16)(acc * invs);
}

// ---------------- pv2: out2[j,d] = sum_i attnT[j,i]*fac[i]*v1[i,d] ---------
// fac[i] = 2^(mrun[jtblk][i] - mf[i]) * invs[i], built once per block in LDS.
__global__ __launch_bounds__(256) void pv2_k(const f16* __restrict__ attnT,
    const f16* __restrict__ v1t, const float* __restrict__ mrun_t,
    const float2* __restrict__ finstats, f16* __restrict__ oacc, int bh0)
{
  __shared__ char vsm[8192];       // Vs [64] swizzled rows
  __shared__ float fac[NSEQ];      // 8 KB
  int z = blockIdx.y, bh = bh0 + z, b = bh >> 3, h = bh & 7;
  int r0 = blockIdx.x * 64;        // j-block == jt index
  int tid = threadIdx.x, w = tid >> 6, lane = tid & 63;
  int lr = lane >> 4, lc = lane & 15;
  {
    const float* mrp = mrun_t + ((size_t)z * 32 + blockIdx.x) * NSEQ;
    const float2* fsp = finstats + (size_t)z * NSEQ;
    for (int i = tid; i < NSEQ; i += 256) {
      float2 fs = fsp[i];
      fac[i] = exp2f(mrp[i] - fs.x) * fs.y;
    }
  }
  __syncthreads();
  int row = tid >> 2, cv = (tid & 3) * 16;
  const f16* vp = v1t + ((size_t)bh * 64 + row) * NSEQ + cv;
  const f16* ap = attnT + ((size_t)z * NSEQ + r0 + 16*w + lc) * NSEQ + 8*lr;
  f32x4 acc[4] = {};
  for (int k0 = 0; k0 < NSEQ; k0 += 64) {
    f16x8 v0 = *(const f16x8*)(vp + k0);
    f16x8 v1 = *(const f16x8*)(vp + k0 + 8);
    f16x8 s0, s1;
    #pragma unroll
    for (int t = 0; t < 8; t++) {
      s0[t] = (f16)((float)v0[t] * fac[cv + k0 + t]);
      s1[t] = (f16)((float)v1[t] * fac[cv + k0 + 8 + t]);
    }
    *(f16x8*)(vsm + LSWZ(row, cv))     = s0;
    *(f16x8*)(vsm + LSWZ(row, cv + 8)) = s1;
    __syncthreads();
    f16x8 a0 = *(const f16x8*)(ap + k0);
    f16x8 a1 = *(const f16x8*)(ap + k0 + 32);
    #pragma unroll
    for (int nt = 0; nt < 4; nt++) {
      acc[nt] = MFMA16(a0, *(const f16x8*)(vsm + LSWZ(16*nt + lc, 8*lr)), acc[nt]);
      acc[nt] = MFMA16(a1, *(const f16x8*)(vsm + LSWZ(16*nt + lc, 32 + 8*lr)), acc[nt]);
    }
    __syncthreads();
  }
  #pragma unroll
  for (int nt = 0; nt < 4; nt++)
    #pragma unroll
    for (int r = 0; r < 4; r++) {
      int rw = r0 + 16*w + 4*lr + r;
      oacc[((size_t)b * NSEQ + rw) * 512 + h * 64 + 16*nt + lc] = (f16)acc[nt][r];
    }
}

extern "C" void kernel_launch(void* const* d_in, const int* in_sizes, int n_in,
                              void* d_out, int out_size, void* d_ws, size_t ws_size,
                              hipStream_t stream) {
  const float* x1   = (const float*)d_in[0];
  const float* x2   = (const float*)d_in[1];
  const float* Wq   = (const float*)d_in[2];
  const float* Wk   = (const float*)d_in[3];
  const float* Wv1  = (const float*)d_in[4];
  const float* Wv2  = (const float*)d_in[5];
  const float* Wrel = (const float*)d_in[6];
  const float* rpb  = (const float*)d_in[7];
  const float* Wo1  = (const float*)d_in[8];
  const float* bo1  = (const float*)d_in[9];
  const float* Wo2  = (const float*)d_in[10];
  const float* bo2  = (const float*)d_in[11];
  float* out = (float*)d_out;

  char* base = (char*)d_ws;
  size_t off = 0;
  auto alloc = [&](size_t bytes) -> void* {
    void* p = base + off; off += (bytes + 255) & ~(size_t)255; return p;
  };
  float*  pos     = (float*) alloc((size_t)NPOS * 192 * 4);
  f16*    relq    = (f16*)   alloc((size_t)NH * NPOS * 64 * 2);
  f16*    qh      = (f16*)   alloc((size_t)16 * NSEQ * 64 * 2);
  f16*    kbh     = (f16*)   alloc((size_t)16 * NSEQ * 64 * 2);
  f16*    v1t     = (f16*)   alloc((size_t)16 * 64 * NSEQ * 2);
  f16*    v2t     = (f16*)   alloc((size_t)16 * 64 * NSEQ * 2);
  f16*    o1acc   = (f16*)   alloc((size_t)2 * NSEQ * 512 * 2);
  f16*    o2acc   = (f16*)   alloc((size_t)2 * NSEQ * 512 * 2);
  float*  o1part  = (float*) alloc((size_t)32 * NSEQ * 64 * 4);     // 32 pieces max
  float2* stats   = (float2*)alloc((size_t)32 * NSEQ * 8);
  float2* finstat = (float2*)alloc((size_t)16 * NSEQ * 8);
  float*  mrun_t  = (float*) alloc((size_t)16 * 32 * NSEQ * 4);
  size_t baseB = off;

  int chunk = 1;
  for (int c = 16; c >= 1; c >>= 1) {
    size_t needB = baseB + (size_t)c * NSEQ * NSEQ * 2;
    if (needB <= ws_size) { chunk = c; break; }
  }
  f16* attnT = (f16*)(base + baseB);
  int nsplit = (chunk >= 16) ? 2 : ((chunk >= 8) ? 4 : 8);
  int jtcnt = 32 / nsplit;

  pos_embed_k<<<(NPOS + 7) / 8, 256, 0, stream>>>(pos);
  relq_k<<<dim3(8, 64), 256, 0, stream>>>(pos, Wrel, relq);
  projx_k<1024, false><<<dim3(16, 64), 256, 0, stream>>>(x1, Wq, Wv1, qh, v1t, nullptr);
  projx_k<512,  true ><<<dim3(16, 64), 256, 0, stream>>>(x2, Wk, Wv2, kbh, v2t, rpb);

  for (int bh0 = 0; bh0 < 16; bh0 += chunk) {
    attn_k<<<dim3(32, nsplit, chunk), 256, 0, stream>>>(
        qh, kbh, relq, v2t, attnT, mrun_t, stats, o1part, bh0, nsplit, jtcnt);
    combine_k<<<chunk * 512, 256, 0, stream>>>(o1part, stats, o1acc, finstat, bh0, nsplit);
    pv2_k<<<dim3(32, chunk), 256, 0, stream>>>(attnT, v1t, mrun_t, finstat, o2acc, bh0);
  }

  outproj_k<<<dim3(16, 128), 256, 0, stream>>>(o1acc, o2acc, Wo1, Wo2, bo1, bo2, out);
}

// Round 13
// 316.638 us; speedup vs baseline: 1.7013x; 1.7013x over previous
//
#include <hip/hip_runtime.h>
#include <math.h>

#define NSEQ 2048
#define NPOS 4095   // 2*NSEQ-1
#define NH   8
#define LOG2E 1.4426950408889634f

typedef _Float16 f16;
typedef f16 f16x8 __attribute__((ext_vector_type(8)));
typedef f16 f16x4 __attribute__((ext_vector_type(4)));
typedef float f32x4 __attribute__((ext_vector_type(4)));

#define MFMA16(a,b,c) __builtin_amdgcn_mfma_f32_16x16x32_f16(a,b,c,0,0,0)
// swizzled LDS byte offset: row stride 128B, 16B-granule XOR on (row&7)
#define LSWZ(row, col) (((row) << 7) + ((((col) << 1)) ^ (((row) & 7) << 4)))

__device__ __forceinline__ f16x8 cvt8(float4 a, float4 b) {
  f16x8 r = {(f16)a.x, (f16)a.y, (f16)a.z, (f16)a.w,
             (f16)b.x, (f16)b.y, (f16)b.z, (f16)b.w};
  return r;
}

// ---------------- positional embedding pos[NPOS][192], one lane per (t,f) ----
__global__ __launch_bounds__(256) void pos_embed_k(float* __restrict__ pos) {
  int t = blockIdx.x * 8 + (threadIdx.x >> 5);
  int f = threadIdx.x & 31;
  if (t >= NPOS) return;
  float dist = (float)(t - (NSEQ - 1));
  float ad = fabsf(dist);
  float sgn = (dist > 0.f) ? 1.f : ((dist < 0.f) ? -1.f : 0.f);
  double mean = 64.0 * (double)(f + 1);       // linspace(64,2048,32)
  double conc = (mean / 32.0) * (mean / 32.0);
  double rate = mean / 1024.0;
  double p = 0.0;
  if (ad > 0.f) {
    double lu = (conc - 1.0) * log((double)ad) - rate * (double)ad;
    double ln = lgamma(conc) - conc * log(rate);
    p = exp(lu - ln);
  }
  float pf = (float)p + 1e-8f;
  float gmax = pf;
  #pragma unroll
  for (int mk = 1; mk <= 16; mk <<= 1) gmax = fmaxf(gmax, __shfl_xor(gmax, mk));
  float fg = pf / gmax;
  float hl = exp2f(3.f + 8.f * (float)f * (1.f / 31.f));
  float fe = exp2f(-ad / hl);
  float cw = exp2f((float)(f + 1)) - 1.f;
  float fc = (cw > ad) ? 1.f : 0.f;
  float* row = pos + (size_t)t * 192;
  row[f]       = fe;       row[32 + f]  = fc;       row[64 + f]  = fg;
  row[96 + f]  = sgn * fe; row[128 + f] = sgn * fc; row[160 + f] = sgn * fg;
}

// ---------------- relq = pos @ Wrel -> f16 [h][NPOS][64], scaled by log2e ---
__global__ __launch_bounds__(256) void relq_k(
    const float* __restrict__ A, const float* __restrict__ W, f16* __restrict__ relq)
{
  __shared__ f16 As[64][56];
  __shared__ f16 Bs[64][56];
  int tid = threadIdx.x, w = tid >> 6, lane = tid & 63, lr = lane >> 4, lc = lane & 15;
  int m0 = blockIdx.y * 64, n0 = blockIdx.x * 64;
  int ar = tid >> 2, ac = (tid & 3) * 8;
  int bk = tid >> 3, bn = (tid & 7) * 8;
  f32x4 acc[4] = {};
  for (int k0 = 0; k0 < 192; k0 += 32) {
    float4 a0 = make_float4(0.f,0.f,0.f,0.f), a1 = a0;
    if (m0 + ar < NPOS) {
      const float* ap = &A[(size_t)(m0 + ar) * 192 + k0 + ac];
      a0 = *(const float4*)ap; a1 = *(const float4*)(ap + 4);
    }
    *(f16x8*)&As[ar][ac] = cvt8(a0, a1);
    const float* bp = &W[(size_t)(k0 + bk) * 512 + n0 + bn];
    float4 b0 = *(const float4*)bp, b1 = *(const float4*)(bp + 4);
    f16 bv[8] = {(f16)b0.x,(f16)b0.y,(f16)b0.z,(f16)b0.w,(f16)b1.x,(f16)b1.y,(f16)b1.z,(f16)b1.w};
    #pragma unroll
    for (int tt = 0; tt < 8; tt++) { int t = (tt + bk) & 7; Bs[bn + t][bk] = bv[t]; }
    __syncthreads();
    f16x8 af = *(const f16x8*)&As[16*w + lc][8*lr];
    #pragma unroll
    for (int nt = 0; nt < 4; nt++) {
      f16x8 bf = *(const f16x8*)&Bs[16*nt + lc][8*lr];
      acc[nt] = MFMA16(af, bf, acc[nt]);
    }
    __syncthreads();
  }
  #pragma unroll
  for (int nt = 0; nt < 4; nt++)
    #pragma unroll
    for (int r = 0; r < 4; r++) {
      int m = m0 + 16*w + 4*lr + r;
      if (m >= NPOS) continue;
      int nn = n0 + 16*nt + lc;
      relq[((size_t)(nn >> 6) * NPOS + m) * 64 + (nn & 63)] = (f16)(acc[nt][r] * LOG2E);
    }
}

// ---------------- input projections (64x64 tile): A[4096,KD] x (W1|W2) -----
// first half  -> O1 head-split; SC1? (*0.125+rpb) : (*log2e)  [kb vs q]
// second half -> O2t TRANSPOSED [bh][d][2048]
template<int KD, bool SC1>
__global__ __launch_bounds__(256) void projx_k(
    const float* __restrict__ A, const float* __restrict__ W1, const float* __restrict__ W2,
    f16* __restrict__ O1, f16* __restrict__ O2t, const float* __restrict__ rpb)
{
  __shared__ f16 As[64][56];
  __shared__ f16 Bs[64][56];
  int tid = threadIdx.x, w = tid >> 6, lane = tid & 63, lr = lane >> 4, lc = lane & 15;
  int m0 = blockIdx.y * 64, n0g = blockIdx.x * 64;
  bool first = (n0g < 512);
  const float* W = first ? W1 : W2;
  int n0 = n0g & 511;
  int ar = tid >> 2, ac = (tid & 3) * 8;
  int bk = tid >> 3, bn = (tid & 7) * 8;
  f32x4 acc[4] = {};
  for (int k0 = 0; k0 < KD; k0 += 32) {
    const float* ap = &A[(size_t)(m0 + ar) * KD + k0 + ac];
    *(f16x8*)&As[ar][ac] = cvt8(*(const float4*)ap, *(const float4*)(ap + 4));
    const float* bp = &W[(size_t)(k0 + bk) * 512 + n0 + bn];
    float4 b0 = *(const float4*)bp, b1 = *(const float4*)(bp + 4);
    f16 bv[8] = {(f16)b0.x,(f16)b0.y,(f16)b0.z,(f16)b0.w,(f16)b1.x,(f16)b1.y,(f16)b1.z,(f16)b1.w};
    #pragma unroll
    for (int tt = 0; tt < 8; tt++) { int t = (tt + bk) & 7; Bs[bn + t][bk] = bv[t]; }
    __syncthreads();
    f16x8 af = *(const f16x8*)&As[16*w + lc][8*lr];
    #pragma unroll
    for (int nt = 0; nt < 4; nt++) {
      f16x8 bf = *(const f16x8*)&Bs[16*nt + lc][8*lr];
      acc[nt] = MFMA16(af, bf, acc[nt]);
    }
    __syncthreads();
  }
  if (first) {
    #pragma unroll
    for (int nt = 0; nt < 4; nt++)
      #pragma unroll
      for (int r = 0; r < 4; r++) {
        int m = m0 + 16*w + 4*lr + r;
        int nn = n0 + 16*nt + lc;
        float vv = acc[nt][r];
        if (SC1) vv = vv * 0.125f + rpb[nn];
        else     vv = vv * LOG2E;
        O1[(((size_t)((m >> 11) * NH + (nn >> 6))) * NSEQ + (m & (NSEQ - 1))) * 64 + (nn & 63)] = (f16)vv;
      }
  } else {
    int mb = m0 + 16*w + 4*lr;
    #pragma unroll
    for (int nt = 0; nt < 4; nt++) {
      int nn = n0 + 16*nt + lc;
      f16x4 pk = {(f16)acc[nt][0], (f16)acc[nt][1], (f16)acc[nt][2], (f16)acc[nt][3]};
      *(f16x4*)&O2t[(((size_t)((mb >> 11) * NH + (nn >> 6))) * 64 + (nn & 63)) * NSEQ + (mb & (NSEQ - 1))] = pk;
    }
  }
}

// ---------------- fused output projections (64x64 tile) ----------------
__global__ __launch_bounds__(256) void outproj_k(
    const f16* __restrict__ o1, const f16* __restrict__ o2,
    const float* __restrict__ Wo1, const float* __restrict__ Wo2,
    const float* __restrict__ bo1, const float* __restrict__ bo2,
    float* __restrict__ out)
{
  __shared__ f16 As[64][56];
  __shared__ f16 Bs[64][56];
  int by = blockIdx.y;
  bool first = (by < 64);
  const f16* A = first ? o1 : o2;
  const float* W = first ? Wo1 : Wo2;
  const float* bias = first ? bo1 : bo2;
  float* O = out + (first ? 0 : (size_t)4096 * 1024);
  int tid = threadIdx.x, w = tid >> 6, lane = tid & 63, lr = lane >> 4, lc = lane & 15;
  int m0 = (by & 63) * 64, n0 = blockIdx.x * 64;
  int ar = tid >> 2, ac = (tid & 3) * 8;
  int bk = tid >> 3, bn = (tid & 7) * 8;
  f32x4 acc[4] = {};
  for (int k0 = 0; k0 < 512; k0 += 32) {
    *(f16x8*)&As[ar][ac] = *(const f16x8*)&A[(size_t)(m0 + ar) * 512 + k0 + ac];
    const float* bp = &W[(size_t)(k0 + bk) * 1024 + n0 + bn];
    float4 b0 = *(const float4*)bp, b1 = *(const float4*)(bp + 4);
    f16 bv[8] = {(f16)b0.x,(f16)b0.y,(f16)b0.z,(f16)b0.w,(f16)b1.x,(f16)b1.y,(f16)b1.z,(f16)b1.w};
    #pragma unroll
    for (int tt = 0; tt < 8; tt++) { int t = (tt + bk) & 7; Bs[bn + t][bk] = bv[t]; }
    __syncthreads();
    f16x8 af = *(const f16x8*)&As[16*w + lc][8*lr];
    #pragma unroll
    for (int nt = 0; nt < 4; nt++) {
      f16x8 bf = *(const f16x8*)&Bs[16*nt + lc][8*lr];
      acc[nt] = MFMA16(af, bf, acc[nt]);
    }
    __syncthreads();
  }
  #pragma unroll
  for (int nt = 0; nt < 4; nt++)
    #pragma unroll
    for (int r = 0; r < 4; r++) {
      int m = m0 + 16*w + 4*lr + r;
      int n = n0 + 16*nt + lc;
      O[(size_t)m * 1024 + n] = acc[nt][r] + bias[n];
    }
}

// ---------------- fused logits + online softmax + out1 PV (split-j) --------
// All logits in log2 domain (q, relq pre-scaled by log2e). Block handles
// jtcnt j-tiles starting at jt0 = split*jtcnt. Outputs per split:
//  attnT[j][i] = 2^(l - m_run_jt), mrun_t[z][jt][i], stats[z*nsplit+split][i]
//  = (m_fin, s), o1part[(z*nsplit+split)][i][d] (f32, 2^m_fin-scaled).
// LDS 40960B, stride-64 XOR-swizzled: QG(Q/G2)@0, KB(+Pw)@8192, R0@16384,
// R1@24576, VS@32768.
// NOTE: plain __launch_bounds__(256) — round 12's (256,4) squeezed VGPRs to
// 64 and spilled to scratch (FETCH_SIZE 581 MB, MfmaUtil 3.3%).
__global__ __launch_bounds__(256) void attn_k(
    const f16* __restrict__ q, const f16* __restrict__ kb,
    const f16* __restrict__ relq, const f16* __restrict__ v2t,
    f16* __restrict__ attnT, float* __restrict__ mrun_t,
    float2* __restrict__ stats, float* __restrict__ o1part,
    int bh0, int nsplit, int jtcnt)
{
  __shared__ char smem[40960];
  char* QG = smem;
  char* KB = smem + 8192;
  char* R0 = smem + 16384;
  char* R1 = smem + 24576;
  char* VS = smem + 32768;
  int z = blockIdx.z, bh = bh0 + z, h = bh & 7;
  int i0 = blockIdx.x * 64;
  int split = blockIdx.y, jt0 = split * jtcnt;
  int tid = threadIdx.x, w = tid >> 6, lane = tid & 63;
  int lr = lane >> 4, lc = lane & 15;
  char* PW = KB + w * 2048;          // per-wave [16] swizzled rows
  int base0 = i0 + 1984;             // (NSEQ-1) + i0 - 63
  int row = tid >> 2, c0 = (tid & 3) * 16;

  {
    const f16* qp = q + ((size_t)bh * NSEQ + i0 + row) * 64 + c0;
    *(f16x8*)(QG + LSWZ(row, c0))     = *(const f16x8*)qp;
    *(f16x8*)(QG + LSWZ(row, c0 + 8)) = *(const f16x8*)(qp + 8);
    // prologue: panel jt0-1 -> slot 1 (jt0 even)
    const f16* rp = relq + ((size_t)h * NPOS + base0 + 64 - 64*jt0 + row) * 64 + c0;
    *(f16x8*)(R1 + LSWZ(row, c0))     = *(const f16x8*)rp;
    *(f16x8*)(R1 + LSWZ(row, c0 + 8)) = *(const f16x8*)(rp + 8);
  }
  __syncthreads();
  f16x8 qa0 = *(const f16x8*)(QG + LSWZ(16*w + lc, 8*lr));
  f16x8 qa1 = *(const f16x8*)(QG + LSWZ(16*w + lc, 32 + 8*lr));

  // tile-jt0 prefetch registers
  const f16* kpb  = kb  + ((size_t)bh * NSEQ + jt0 * 64 + row) * 64 + c0;
  const f16* vpb  = v2t + ((size_t)bh * 64 + row) * NSEQ + jt0 * 64 + c0;
  const f16* rpb0 = relq + ((size_t)h * NPOS + base0 - 64*jt0 + row) * 64 + c0;
  f16x8 skb0 = *(const f16x8*)kpb,  skb1 = *(const f16x8*)(kpb + 8);
  f16x8 sv0  = *(const f16x8*)vpb,  sv1  = *(const f16x8*)(vpb + 8);
  f16x8 sr0  = *(const f16x8*)rpb0, sr1  = *(const f16x8*)(rpb0 + 8);

  float m_run[4], ssum[4], mreg[4] = {};
  f32x4 o1a[4] = {};
  #pragma unroll
  for (int r = 0; r < 4; r++) { m_run[r] = -1e30f; ssum[r] = 0.f; }

  for (int jt = jt0; jt < jt0 + jtcnt; jt++) {
    int j0 = jt * 64;
    char* RsA = (jt & 1) ? R1 : R0;   // panel jt: n in [0,64)
    char* RsB = (jt & 1) ? R0 : R1;   // panel jt-1: n in [64,128)
    *(f16x8*)(KB + LSWZ(row, c0))      = skb0;  *(f16x8*)(KB + LSWZ(row, c0 + 8))  = skb1;
    *(f16x8*)(VS + LSWZ(row, c0))      = sv0;   *(f16x8*)(VS + LSWZ(row, c0 + 8))  = sv1;
    *(f16x8*)(RsA + LSWZ(row, c0))     = sr0;   *(f16x8*)(RsA + LSWZ(row, c0 + 8)) = sr1;
    __syncthreads();   // s1: staging visible
    f32x4 cacc[4];
    f16x8 ka0 = {}, ka1 = {};
    __builtin_amdgcn_s_setprio(1);
    #pragma unroll
    for (int y = 0; y < 4; y++) {
      f16x8 b0 = *(const f16x8*)(KB + LSWZ(16*y + lc, 8*lr));
      f16x8 b1 = *(const f16x8*)(KB + LSWZ(16*y + lc, 32 + 8*lr));
      f32x4 t = {};
      t = MFMA16(qa0, b0, t);
      t = MFMA16(qa1, b1, t);
      cacc[y] = t;
      if (y == w) { ka0 = b0; ka1 = b1; }
    }
    __builtin_amdgcn_s_setprio(0);
    // G blocks: only g in [3-w, 7-w] contribute
    #pragma unroll
    for (int gg = 0; gg < 5; gg++) {
      int g = 3 - w + gg;
      char* Rg = (g < 4) ? RsA : RsB;
      int grow = 16 * (g & 3) + lc;
      f32x4 ga = {};
      ga = MFMA16(ka0, *(const f16x8*)(Rg + LSWZ(grow, 8*lr)), ga);
      ga = MFMA16(ka1, *(const f16x8*)(Rg + LSWZ(grow, 32 + 8*lr)), ga);
      int jj = 16*w + 4*lr;
      #pragma unroll
      for (int r = 0; r < 4; r++) {
        int ii = 16*g + lc + jj + r - 63;   // i = n + j - 63
        if ((unsigned)ii < 64u) *(f16*)(QG + LSWZ(jj + r, ii)) = (f16)ga[r];
      }
    }
    // prefetch next tile into registers (hides under softmax+PV)
    {
      int jn = (jt < jt0 + jtcnt - 1) ? jt + 1 : jt;
      const f16* kpn = kb  + ((size_t)bh * NSEQ + jn * 64 + row) * 64 + c0;
      const f16* vpn = v2t + ((size_t)bh * 64 + row) * NSEQ + jn * 64 + c0;
      const f16* rpn = relq + ((size_t)h * NPOS + base0 - 64 * jn + row) * 64 + c0;
      skb0 = *(const f16x8*)kpn;  skb1 = *(const f16x8*)(kpn + 8);
      sv0  = *(const f16x8*)vpn;  sv1  = *(const f16x8*)(vpn + 8);
      sr0  = *(const f16x8*)rpn;  sr1  = *(const f16x8*)(rpn + 8);
    }
    __syncthreads();   // s2: G2 complete; KB frag reads done -> Pw overlay safe
    float l[4][4];
    #pragma unroll
    for (int y = 0; y < 4; y++) {
      f16x4 gv = *(const f16x4*)(QG + LSWZ(16*y + lc, 16*w + 4*lr));
      #pragma unroll
      for (int r = 0; r < 4; r++) l[y][r] = cacc[y][r] + (float)gv[r];
    }
    float pvr[4][4];   // [r][y]
    #pragma unroll
    for (int r = 0; r < 4; r++) {
      float tm = fmaxf(fmaxf(l[0][r], l[1][r]), fmaxf(l[2][r], l[3][r]));
      #pragma unroll
      for (int mk = 1; mk <= 8; mk <<= 1) tm = fmaxf(tm, __shfl_xor(tm, mk));
      if (tm > m_run[r]) {
        float sc = exp2f(m_run[r] - tm);
        ssum[r] *= sc;
        #pragma unroll
        for (int nt = 0; nt < 4; nt++) o1a[nt][r] *= sc;
        m_run[r] = tm;
      }
      float mnew = m_run[r];
      float ps = 0.f;
      #pragma unroll
      for (int y = 0; y < 4; y++) {
        float p = exp2f(l[y][r] - mnew);
        ps += p;
        pvr[r][y] = p;
        *(f16*)(PW + LSWZ(4*lr + r, 16*y + lc)) = (f16)p;
      }
      ssum[r] += ps;
      if (lc == jt - jt0) mreg[r] = mnew;   // lane lc owns tile jt0+lc
    }
    // transposed P store, direct from registers: attnT[j][i]
    #pragma unroll
    for (int y = 0; y < 4; y++) {
      f16x4 pk = {(f16)pvr[0][y], (f16)pvr[1][y], (f16)pvr[2][y], (f16)pvr[3][y]};
      *(f16x4*)&attnT[((size_t)z * NSEQ + j0 + 16*y + lc) * NSEQ + i0 + 16*w + 4*lr] = pk;
    }
    // out1 PV (Pw per-wave, lgkmcnt-ordered)
    {
      f16x8 pa0 = *(const f16x8*)(PW + LSWZ(lc, 8*lr));
      f16x8 pa1 = *(const f16x8*)(PW + LSWZ(lc, 32 + 8*lr));
      __builtin_amdgcn_s_setprio(1);
      #pragma unroll
      for (int nt = 0; nt < 4; nt++) {
        f16x8 vf0 = *(const f16x8*)(VS + LSWZ(16*nt + lc, 8*lr));
        f16x8 vf1 = *(const f16x8*)(VS + LSWZ(16*nt + lc, 32 + 8*lr));
        o1a[nt] = MFMA16(pa0, vf0, o1a[nt]);
        o1a[nt] = MFMA16(pa1, vf1, o1a[nt]);
      }
      __builtin_amdgcn_s_setprio(0);
    }
    __syncthreads();   // s3: all LDS reads done -> restage ok
  }
  // epilogue: per-row s reduce; write mrun_t / stats / o1part
  #pragma unroll
  for (int r = 0; r < 4; r++) {
    float s = ssum[r];
    #pragma unroll
    for (int mk = 1; mk <= 8; mk <<= 1) s += __shfl_xor(s, mk);
    int il = 16*w + 4*lr + r;
    if (lc < jtcnt)
      mrun_t[((size_t)z * 32 + jt0 + lc) * NSEQ + i0 + il] = mreg[r];
    if (lc == 0) {
      float2 st; st.x = m_run[r]; st.y = s;
      stats[((size_t)z * nsplit + split) * NSEQ + i0 + il] = st;
    }
  }
  #pragma unroll
  for (int nt = 0; nt < 4; nt++)
    #pragma unroll
    for (int r = 0; r < 4; r++) {
      int il = 16*w + 4*lr + r;
      o1part[(((size_t)z * nsplit + split) * NSEQ + i0 + il) * 64 + 16*nt + lc] = o1a[nt][r];
    }
}

// ---------------- combine: merge splits -> o1acc + finstats(mf, 1/s) -------
__global__ __launch_bounds__(256) void combine_k(
    const float* __restrict__ o1part, const float2* __restrict__ stats,
    f16* __restrict__ o1acc, float2* __restrict__ finstats,
    int bh0, int nsplit)
{
  int rid = blockIdx.x * 4 + (threadIdx.x >> 6);
  int d = threadIdx.x & 63;
  int z = rid >> 11, i = rid & 2047;
  int bh = bh0 + z, b = bh >> 3, h = bh & 7;
  float mf = -1e30f;
  #pragma unroll 2
  for (int sp = 0; sp < nsplit; sp++)
    mf = fmaxf(mf, stats[((size_t)z * nsplit + sp) * NSEQ + i].x);
  float s = 0.f, acc = 0.f;
  #pragma unroll 2
  for (int sp = 0; sp < nsplit; sp++) {
    float2 st = stats[((size_t)z * nsplit + sp) * NSEQ + i];
    float f = exp2f(st.x - mf);
    s += st.y * f;
    acc += o1part[(((size_t)z * nsplit + sp) * NSEQ + i) * 64 + d] * f;
  }
  float invs = 1.f / s;
  if (d == 0) { float2 fs; fs.x = mf; fs.y = invs; finstats[(size_t)z * NSEQ + i] = fs; }
  o1acc[((size_t)b * NSEQ + i) * 512 + h * 64 + d] = (f16)(acc * invs);
}

// ---------------- pv2: out2[j,d] = sum_i attnT[j,i]*fac[i]*v1[i,d] ---------
// fac[i] = 2^(mrun[jtblk][i] - mf[i]) * invs[i], built once per block in LDS.
__global__ __launch_bounds__(256) void pv2_k(const f16* __restrict__ attnT,
    const f16* __restrict__ v1t, const float* __restrict__ mrun_t,
    const float2* __restrict__ finstats, f16* __restrict__ oacc, int bh0)
{
  __shared__ char vsm[8192];       // Vs [64] swizzled rows
  __shared__ float fac[NSEQ];      // 8 KB
  int z = blockIdx.y, bh = bh0 + z, b = bh >> 3, h = bh & 7;
  int r0 = blockIdx.x * 64;        // j-block == jt index
  int tid = threadIdx.x, w = tid >> 6, lane = tid & 63;
  int lr = lane >> 4, lc = lane & 15;
  {
    const float* mrp = mrun_t + ((size_t)z * 32 + blockIdx.x) * NSEQ;
    const float2* fsp = finstats + (size_t)z * NSEQ;
    for (int i = tid; i < NSEQ; i += 256) {
      float2 fs = fsp[i];
      fac[i] = exp2f(mrp[i] - fs.x) * fs.y;
    }
  }
  __syncthreads();
  int row = tid >> 2, cv = (tid & 3) * 16;
  const f16* vp = v1t + ((size_t)bh * 64 + row) * NSEQ + cv;
  const f16* ap = attnT + ((size_t)z * NSEQ + r0 + 16*w + lc) * NSEQ + 8*lr;
  f32x4 acc[4] = {};
  for (int k0 = 0; k0 < NSEQ; k0 += 64) {
    f16x8 v0 = *(const f16x8*)(vp + k0);
    f16x8 v1 = *(const f16x8*)(vp + k0 + 8);
    f16x8 s0, s1;
    #pragma unroll
    for (int t = 0; t < 8; t++) {
      s0[t] = (f16)((float)v0[t] * fac[cv + k0 + t]);
      s1[t] = (f16)((float)v1[t] * fac[cv + k0 + 8 + t]);
    }
    *(f16x8*)(vsm + LSWZ(row, cv))     = s0;
    *(f16x8*)(vsm + LSWZ(row, cv + 8)) = s1;
    __syncthreads();
    f16x8 a0 = *(const f16x8*)(ap + k0);
    f16x8 a1 = *(const f16x8*)(ap + k0 + 32);
    #pragma unroll
    for (int nt = 0; nt < 4; nt++) {
      acc[nt] = MFMA16(a0, *(const f16x8*)(vsm + LSWZ(16*nt + lc, 8*lr)), acc[nt]);
      acc[nt] = MFMA16(a1, *(const f16x8*)(vsm + LSWZ(16*nt + lc, 32 + 8*lr)), acc[nt]);
    }
    __syncthreads();
  }
  #pragma unroll
  for (int nt = 0; nt < 4; nt++)
    #pragma unroll
    for (int r = 0; r < 4; r++) {
      int rw = r0 + 16*w + 4*lr + r;
      oacc[((size_t)b * NSEQ + rw) * 512 + h * 64 + 16*nt + lc] = (f16)acc[nt][r];
    }
}

extern "C" void kernel_launch(void* const* d_in, const int* in_sizes, int n_in,
                              void* d_out, int out_size, void* d_ws, size_t ws_size,
                              hipStream_t stream) {
  const float* x1   = (const float*)d_in[0];
  const float* x2   = (const float*)d_in[1];
  const float* Wq   = (const float*)d_in[2];
  const float* Wk   = (const float*)d_in[3];
  const float* Wv1  = (const float*)d_in[4];
  const float* Wv2  = (const float*)d_in[5];
  const float* Wrel = (const float*)d_in[6];
  const float* rpb  = (const float*)d_in[7];
  const float* Wo1  = (const float*)d_in[8];
  const float* bo1  = (const float*)d_in[9];
  const float* Wo2  = (const float*)d_in[10];
  const float* bo2  = (const float*)d_in[11];
  float* out = (float*)d_out;

  char* base = (char*)d_ws;
  size_t off = 0;
  auto alloc = [&](size_t bytes) -> void* {
    void* p = base + off; off += (bytes + 255) & ~(size_t)255; return p;
  };
  float*  pos     = (float*) alloc((size_t)NPOS * 192 * 4);
  f16*    relq    = (f16*)   alloc((size_t)NH * NPOS * 64 * 2);
  f16*    qh      = (f16*)   alloc((size_t)16 * NSEQ * 64 * 2);
  f16*    kbh     = (f16*)   alloc((size_t)16 * NSEQ * 64 * 2);
  f16*    v1t     = (f16*)   alloc((size_t)16 * 64 * NSEQ * 2);
  f16*    v2t     = (f16*)   alloc((size_t)16 * 64 * NSEQ * 2);
  f16*    o1acc   = (f16*)   alloc((size_t)2 * NSEQ * 512 * 2);
  f16*    o2acc   = (f16*)   alloc((size_t)2 * NSEQ * 512 * 2);
  float*  o1part  = (float*) alloc((size_t)32 * NSEQ * 64 * 4);     // 32 pieces max
  float2* stats   = (float2*)alloc((size_t)32 * NSEQ * 8);
  float2* finstat = (float2*)alloc((size_t)16 * NSEQ * 8);
  float*  mrun_t  = (float*) alloc((size_t)16 * 32 * NSEQ * 4);
  size_t baseB = off;

  int chunk = 1;
  for (int c = 16; c >= 1; c >>= 1) {
    size_t needB = baseB + (size_t)c * NSEQ * NSEQ * 2;
    if (needB <= ws_size) { chunk = c; break; }
  }
  f16* attnT = (f16*)(base + baseB);
  int nsplit = (chunk >= 16) ? 2 : ((chunk >= 8) ? 4 : 8);
  int jtcnt = 32 / nsplit;

  pos_embed_k<<<(NPOS + 7) / 8, 256, 0, stream>>>(pos);
  relq_k<<<dim3(8, 64), 256, 0, stream>>>(pos, Wrel, relq);
  projx_k<1024, false><<<dim3(16, 64), 256, 0, stream>>>(x1, Wq, Wv1, qh, v1t, nullptr);
  projx_k<512,  true ><<<dim3(16, 64), 256, 0, stream>>>(x2, Wk, Wv2, kbh, v2t, rpb);

  for (int bh0 = 0; bh0 < 16; bh0 += chunk) {
    attn_k<<<dim3(32, nsplit, chunk), 256, 0, stream>>>(
        qh, kbh, relq, v2t, attnT, mrun_t, stats, o1part, bh0, nsplit, jtcnt);
    combine_k<<<chunk * 512, 256, 0, stream>>>(o1part, stats, o1acc, finstat, bh0, nsplit);
    pv2_k<<<dim3(32, chunk), 256, 0, stream>>>(attnT, v1t, mrun_t, finstat, o2acc, bh0);
  }

  outproj_k<<<dim3(16, 128), 256, 0, stream>>>(o1acc, o2acc, Wo1, Wo2, bo1, bo2, out);
}

// Round 14
// 302.358 us; speedup vs baseline: 1.7817x; 1.0472x over previous
//
#include <hip/hip_runtime.h>
#include <math.h>

#define NSEQ 2048
#define NPOS 4095   // 2*NSEQ-1
#define NH   8
#define LOG2E 1.4426950408889634f

typedef _Float16 f16;
typedef f16 f16x8 __attribute__((ext_vector_type(8)));
typedef f16 f16x4 __attribute__((ext_vector_type(4)));
typedef float f32x4 __attribute__((ext_vector_type(4)));

#define MFMA16(a,b,c) __builtin_amdgcn_mfma_f32_16x16x32_f16(a,b,c,0,0,0)
// swizzled LDS byte offset: row stride 128B, 16B-granule XOR on (row&7)
#define LSWZ(row, col) (((row) << 7) + ((((col) << 1)) ^ (((row) & 7) << 4)))

__device__ __forceinline__ f16x8 cvt8(float4 a, float4 b) {
  f16x8 r = {(f16)a.x, (f16)a.y, (f16)a.z, (f16)a.w,
             (f16)b.x, (f16)b.y, (f16)b.z, (f16)b.w};
  return r;
}
__device__ __forceinline__ f16x8 scale8(f16x8 v, float4 a, float4 b) {
  f16x8 r;
  r[0] = (f16)((float)v[0] * a.x); r[1] = (f16)((float)v[1] * a.y);
  r[2] = (f16)((float)v[2] * a.z); r[3] = (f16)((float)v[3] * a.w);
  r[4] = (f16)((float)v[4] * b.x); r[5] = (f16)((float)v[5] * b.y);
  r[6] = (f16)((float)v[6] * b.z); r[7] = (f16)((float)v[7] * b.w);
  return r;
}

// ---------------- positional embedding pos[NPOS][192], one lane per (t,f) ----
__global__ __launch_bounds__(256) void pos_embed_k(float* __restrict__ pos) {
  int t = blockIdx.x * 8 + (threadIdx.x >> 5);
  int f = threadIdx.x & 31;
  if (t >= NPOS) return;
  float dist = (float)(t - (NSEQ - 1));
  float ad = fabsf(dist);
  float sgn = (dist > 0.f) ? 1.f : ((dist < 0.f) ? -1.f : 0.f);
  double mean = 64.0 * (double)(f + 1);       // linspace(64,2048,32)
  double conc = (mean / 32.0) * (mean / 32.0);
  double rate = mean / 1024.0;
  double p = 0.0;
  if (ad > 0.f) {
    double lu = (conc - 1.0) * log((double)ad) - rate * (double)ad;
    double ln = lgamma(conc) - conc * log(rate);
    p = exp(lu - ln);
  }
  float pf = (float)p + 1e-8f;
  float gmax = pf;
  #pragma unroll
  for (int mk = 1; mk <= 16; mk <<= 1) gmax = fmaxf(gmax, __shfl_xor(gmax, mk));
  float fg = pf / gmax;
  float hl = exp2f(3.f + 8.f * (float)f * (1.f / 31.f));
  float fe = exp2f(-ad / hl);
  float cw = exp2f((float)(f + 1)) - 1.f;
  float fc = (cw > ad) ? 1.f : 0.f;
  float* row = pos + (size_t)t * 192;
  row[f]       = fe;       row[32 + f]  = fc;       row[64 + f]  = fg;
  row[96 + f]  = sgn * fe; row[128 + f] = sgn * fc; row[160 + f] = sgn * fg;
}

// ---------------- relq = pos @ Wrel -> f16 [h][NPOS][64], scaled by log2e ---
__global__ __launch_bounds__(256) void relq_k(
    const float* __restrict__ A, const float* __restrict__ W, f16* __restrict__ relq)
{
  __shared__ f16 As[64][56];
  __shared__ f16 Bs[64][56];
  int tid = threadIdx.x, w = tid >> 6, lane = tid & 63, lr = lane >> 4, lc = lane & 15;
  int m0 = blockIdx.y * 64, n0 = blockIdx.x * 64;
  int ar = tid >> 2, ac = (tid & 3) * 8;
  int bk = tid >> 3, bn = (tid & 7) * 8;
  f32x4 acc[4] = {};
  for (int k0 = 0; k0 < 192; k0 += 32) {
    float4 a0 = make_float4(0.f,0.f,0.f,0.f), a1 = a0;
    if (m0 + ar < NPOS) {
      const float* ap = &A[(size_t)(m0 + ar) * 192 + k0 + ac];
      a0 = *(const float4*)ap; a1 = *(const float4*)(ap + 4);
    }
    *(f16x8*)&As[ar][ac] = cvt8(a0, a1);
    const float* bp = &W[(size_t)(k0 + bk) * 512 + n0 + bn];
    float4 b0 = *(const float4*)bp, b1 = *(const float4*)(bp + 4);
    f16 bv[8] = {(f16)b0.x,(f16)b0.y,(f16)b0.z,(f16)b0.w,(f16)b1.x,(f16)b1.y,(f16)b1.z,(f16)b1.w};
    #pragma unroll
    for (int tt = 0; tt < 8; tt++) { int t = (tt + bk) & 7; Bs[bn + t][bk] = bv[t]; }
    __syncthreads();
    f16x8 af = *(const f16x8*)&As[16*w + lc][8*lr];
    #pragma unroll
    for (int nt = 0; nt < 4; nt++) {
      f16x8 bf = *(const f16x8*)&Bs[16*nt + lc][8*lr];
      acc[nt] = MFMA16(af, bf, acc[nt]);
    }
    __syncthreads();
  }
  #pragma unroll
  for (int nt = 0; nt < 4; nt++)
    #pragma unroll
    for (int r = 0; r < 4; r++) {
      int m = m0 + 16*w + 4*lr + r;
      if (m >= NPOS) continue;
      int nn = n0 + 16*nt + lc;
      relq[((size_t)(nn >> 6) * NPOS + m) * 64 + (nn & 63)] = (f16)(acc[nt][r] * LOG2E);
    }
}

// ---------------- input projections (64x64 tile): A[4096,KD] x (W1|W2) -----
// first half  -> O1 head-split; SC1? (*0.125+rpb) : (*log2e)  [kb vs q]
// second half -> O2t TRANSPOSED [bh][d][2048]
template<int KD, bool SC1>
__global__ __launch_bounds__(256) void projx_k(
    const float* __restrict__ A, const float* __restrict__ W1, const float* __restrict__ W2,
    f16* __restrict__ O1, f16* __restrict__ O2t, const float* __restrict__ rpb)
{
  __shared__ f16 As[64][56];
  __shared__ f16 Bs[64][56];
  int tid = threadIdx.x, w = tid >> 6, lane = tid & 63, lr = lane >> 4, lc = lane & 15;
  int m0 = blockIdx.y * 64, n0g = blockIdx.x * 64;
  bool first = (n0g < 512);
  const float* W = first ? W1 : W2;
  int n0 = n0g & 511;
  int ar = tid >> 2, ac = (tid & 3) * 8;
  int bk = tid >> 3, bn = (tid & 7) * 8;
  f32x4 acc[4] = {};
  for (int k0 = 0; k0 < KD; k0 += 32) {
    const float* ap = &A[(size_t)(m0 + ar) * KD + k0 + ac];
    *(f16x8*)&As[ar][ac] = cvt8(*(const float4*)ap, *(const float4*)(ap + 4));
    const float* bp = &W[(size_t)(k0 + bk) * 512 + n0 + bn];
    float4 b0 = *(const float4*)bp, b1 = *(const float4*)(bp + 4);
    f16 bv[8] = {(f16)b0.x,(f16)b0.y,(f16)b0.z,(f16)b0.w,(f16)b1.x,(f16)b1.y,(f16)b1.z,(f16)b1.w};
    #pragma unroll
    for (int tt = 0; tt < 8; tt++) { int t = (tt + bk) & 7; Bs[bn + t][bk] = bv[t]; }
    __syncthreads();
    f16x8 af = *(const f16x8*)&As[16*w + lc][8*lr];
    #pragma unroll
    for (int nt = 0; nt < 4; nt++) {
      f16x8 bf = *(const f16x8*)&Bs[16*nt + lc][8*lr];
      acc[nt] = MFMA16(af, bf, acc[nt]);
    }
    __syncthreads();
  }
  if (first) {
    #pragma unroll
    for (int nt = 0; nt < 4; nt++)
      #pragma unroll
      for (int r = 0; r < 4; r++) {
        int m = m0 + 16*w + 4*lr + r;
        int nn = n0 + 16*nt + lc;
        float vv = acc[nt][r];
        if (SC1) vv = vv * 0.125f + rpb[nn];
        else     vv = vv * LOG2E;
        O1[(((size_t)((m >> 11) * NH + (nn >> 6))) * NSEQ + (m & (NSEQ - 1))) * 64 + (nn & 63)] = (f16)vv;
      }
  } else {
    int mb = m0 + 16*w + 4*lr;
    #pragma unroll
    for (int nt = 0; nt < 4; nt++) {
      int nn = n0 + 16*nt + lc;
      f16x4 pk = {(f16)acc[nt][0], (f16)acc[nt][1], (f16)acc[nt][2], (f16)acc[nt][3]};
      *(f16x4*)&O2t[(((size_t)((mb >> 11) * NH + (nn >> 6))) * 64 + (nn & 63)) * NSEQ + (mb & (NSEQ - 1))] = pk;
    }
  }
}

// ---------------- fused output projections (64x64 tile) ----------------
__global__ __launch_bounds__(256) void outproj_k(
    const f16* __restrict__ o1, const f16* __restrict__ o2,
    const float* __restrict__ Wo1, const float* __restrict__ Wo2,
    const float* __restrict__ bo1, const float* __restrict__ bo2,
    float* __restrict__ out)
{
  __shared__ f16 As[64][56];
  __shared__ f16 Bs[64][56];
  int by = blockIdx.y;
  bool first = (by < 64);
  const f16* A = first ? o1 : o2;
  const float* W = first ? Wo1 : Wo2;
  const float* bias = first ? bo1 : bo2;
  float* O = out + (first ? 0 : (size_t)4096 * 1024);
  int tid = threadIdx.x, w = tid >> 6, lane = tid & 63, lr = lane >> 4, lc = lane & 15;
  int m0 = (by & 63) * 64, n0 = blockIdx.x * 64;
  int ar = tid >> 2, ac = (tid & 3) * 8;
  int bk = tid >> 3, bn = (tid & 7) * 8;
  f32x4 acc[4] = {};
  for (int k0 = 0; k0 < 512; k0 += 32) {
    *(f16x8*)&As[ar][ac] = *(const f16x8*)&A[(size_t)(m0 + ar) * 512 + k0 + ac];
    const float* bp = &W[(size_t)(k0 + bk) * 1024 + n0 + bn];
    float4 b0 = *(const float4*)bp, b1 = *(const float4*)(bp + 4);
    f16 bv[8] = {(f16)b0.x,(f16)b0.y,(f16)b0.z,(f16)b0.w,(f16)b1.x,(f16)b1.y,(f16)b1.z,(f16)b1.w};
    #pragma unroll
    for (int tt = 0; tt < 8; tt++) { int t = (tt + bk) & 7; Bs[bn + t][bk] = bv[t]; }
    __syncthreads();
    f16x8 af = *(const f16x8*)&As[16*w + lc][8*lr];
    #pragma unroll
    for (int nt = 0; nt < 4; nt++) {
      f16x8 bf = *(const f16x8*)&Bs[16*nt + lc][8*lr];
      acc[nt] = MFMA16(af, bf, acc[nt]);
    }
    __syncthreads();
  }
  #pragma unroll
  for (int nt = 0; nt < 4; nt++)
    #pragma unroll
    for (int r = 0; r < 4; r++) {
      int m = m0 + 16*w + 4*lr + r;
      int n = n0 + 16*nt + lc;
      O[(size_t)m * 1024 + n] = acc[nt][r] + bias[n];
    }
}

// ---------------- fused logits + online softmax + out1 PV ----------------
// Log2-domain logits (q, relq pre-scaled by log2e). One block per (i0, z);
// jt loops over all 32 j-tiles (round-9 structure — split-j reverted: the
// o1part/combine path cost more than the occupancy it bought).
// Writes attnT[j][i] = 2^(l - m_run_jt) (f16x4 direct from regs),
// fac_t[z][jt][i] = 2^(m_jt - m_fin)/s, o1acc normalized.
// LDS 40960B, stride-64 XOR-swizzled: QG(Q/G2)@0, KB(+PW)@8192, R0@16384,
// R1@24576, VS@32768.
__global__ __launch_bounds__(256) void attn_k(
    const f16* __restrict__ q, const f16* __restrict__ kb,
    const f16* __restrict__ relq, const f16* __restrict__ v2t,
    f16* __restrict__ attnT, float* __restrict__ fac_t,
    f16* __restrict__ o1acc, int bh0)
{
  __shared__ char smem[40960];
  char* QG = smem;
  char* KB = smem + 8192;
  char* R0 = smem + 16384;
  char* R1 = smem + 24576;
  char* VS = smem + 32768;
  int z = blockIdx.y, bh = bh0 + z, b = bh >> 3, h = bh & 7;
  int i0 = blockIdx.x * 64;
  int tid = threadIdx.x, w = tid >> 6, lane = tid & 63;
  int lr = lane >> 4, lc = lane & 15;
  char* PW = KB + w * 2048;          // per-wave [16] swizzled rows
  int base0 = i0 + 1984;             // (NSEQ-1) + i0 - 63
  int row = tid >> 2, c0 = (tid & 3) * 16;

  {
    const f16* qp = q + ((size_t)bh * NSEQ + i0 + row) * 64 + c0;
    *(f16x8*)(QG + LSWZ(row, c0))     = *(const f16x8*)qp;
    *(f16x8*)(QG + LSWZ(row, c0 + 8)) = *(const f16x8*)(qp + 8);
    // prologue: panel -1 -> R1 (jt=0 uses RsA=R0, RsB=R1)
    const f16* rp = relq + ((size_t)h * NPOS + base0 + 64 + row) * 64 + c0;
    *(f16x8*)(R1 + LSWZ(row, c0))     = *(const f16x8*)rp;
    *(f16x8*)(R1 + LSWZ(row, c0 + 8)) = *(const f16x8*)(rp + 8);
  }
  __syncthreads();
  f16x8 qa0 = *(const f16x8*)(QG + LSWZ(16*w + lc, 8*lr));
  f16x8 qa1 = *(const f16x8*)(QG + LSWZ(16*w + lc, 32 + 8*lr));

  // tile-0 prefetch registers
  const f16* kpb  = kb  + ((size_t)bh * NSEQ + row) * 64 + c0;
  const f16* vpb  = v2t + ((size_t)bh * 64 + row) * NSEQ + c0;
  const f16* rpb0 = relq + ((size_t)h * NPOS + base0 + row) * 64 + c0;
  f16x8 skb0 = *(const f16x8*)kpb,  skb1 = *(const f16x8*)(kpb + 8);
  f16x8 sv0  = *(const f16x8*)vpb,  sv1  = *(const f16x8*)(vpb + 8);
  f16x8 sr0  = *(const f16x8*)rpb0, sr1  = *(const f16x8*)(rpb0 + 8);

  float m_run[4], ssum[4];
  float mreg0[4] = {}, mreg1[4] = {};
  f32x4 o1a[4] = {};
  #pragma unroll
  for (int r = 0; r < 4; r++) { m_run[r] = -1e30f; ssum[r] = 0.f; }

  for (int jt = 0; jt < 32; jt++) {
    int j0 = jt * 64;
    char* RsA = (jt & 1) ? R1 : R0;   // panel jt: n in [0,64)
    char* RsB = (jt & 1) ? R0 : R1;   // panel jt-1: n in [64,128)
    *(f16x8*)(KB + LSWZ(row, c0))      = skb0;  *(f16x8*)(KB + LSWZ(row, c0 + 8))  = skb1;
    *(f16x8*)(VS + LSWZ(row, c0))      = sv0;   *(f16x8*)(VS + LSWZ(row, c0 + 8))  = sv1;
    *(f16x8*)(RsA + LSWZ(row, c0))     = sr0;   *(f16x8*)(RsA + LSWZ(row, c0 + 8)) = sr1;
    __syncthreads();   // s1: staging visible
    f32x4 cacc[4];
    f16x8 ka0 = {}, ka1 = {};
    __builtin_amdgcn_s_setprio(1);
    #pragma unroll
    for (int y = 0; y < 4; y++) {
      f16x8 b0 = *(const f16x8*)(KB + LSWZ(16*y + lc, 8*lr));
      f16x8 b1 = *(const f16x8*)(KB + LSWZ(16*y + lc, 32 + 8*lr));
      f32x4 t = {};
      t = MFMA16(qa0, b0, t);
      t = MFMA16(qa1, b1, t);
      cacc[y] = t;
      if (y == w) { ka0 = b0; ka1 = b1; }
    }
    __builtin_amdgcn_s_setprio(0);
    // G blocks: only g in [3-w, 7-w] contribute
    #pragma unroll
    for (int gg = 0; gg < 5; gg++) {
      int g = 3 - w + gg;
      char* Rg = (g < 4) ? RsA : RsB;
      int grow = 16 * (g & 3) + lc;
      f32x4 ga = {};
      ga = MFMA16(ka0, *(const f16x8*)(Rg + LSWZ(grow, 8*lr)), ga);
      ga = MFMA16(ka1, *(const f16x8*)(Rg + LSWZ(grow, 32 + 8*lr)), ga);
      int jj = 16*w + 4*lr;
      #pragma unroll
      for (int r = 0; r < 4; r++) {
        int ii = 16*g + lc + jj + r - 63;   // i = n + j - 63
        if ((unsigned)ii < 64u) *(f16*)(QG + LSWZ(jj + r, ii)) = (f16)ga[r];
      }
    }
    // prefetch next tile into registers (hides under softmax+PV)
    {
      int jn = (jt < 31) ? jt + 1 : 31;
      const f16* kpn = kb  + ((size_t)bh * NSEQ + jn * 64 + row) * 64 + c0;
      const f16* vpn = v2t + ((size_t)bh * 64 + row) * NSEQ + jn * 64 + c0;
      const f16* rpn = relq + ((size_t)h * NPOS + base0 - 64 * jn + row) * 64 + c0;
      skb0 = *(const f16x8*)kpn;  skb1 = *(const f16x8*)(kpn + 8);
      sv0  = *(const f16x8*)vpn;  sv1  = *(const f16x8*)(vpn + 8);
      sr0  = *(const f16x8*)rpn;  sr1  = *(const f16x8*)(rpn + 8);
    }
    __syncthreads();   // s2: G2 complete; KB frag reads done -> PW overlay safe
    float l[4][4];
    #pragma unroll
    for (int y = 0; y < 4; y++) {
      f16x4 gv = *(const f16x4*)(QG + LSWZ(16*y + lc, 16*w + 4*lr));
      #pragma unroll
      for (int r = 0; r < 4; r++) l[y][r] = cacc[y][r] + (float)gv[r];
    }
    float pvr[4][4];   // [r][y]
    #pragma unroll
    for (int r = 0; r < 4; r++) {
      float tm = fmaxf(fmaxf(l[0][r], l[1][r]), fmaxf(l[2][r], l[3][r]));
      #pragma unroll
      for (int mk = 1; mk <= 8; mk <<= 1) tm = fmaxf(tm, __shfl_xor(tm, mk));
      if (tm > m_run[r]) {
        float sc = exp2f(m_run[r] - tm);
        ssum[r] *= sc;
        #pragma unroll
        for (int nt = 0; nt < 4; nt++) o1a[nt][r] *= sc;
        m_run[r] = tm;
      }
      float mnew = m_run[r];
      float ps = 0.f;
      #pragma unroll
      for (int y = 0; y < 4; y++) {
        float p = exp2f(l[y][r] - mnew);
        ps += p;
        pvr[r][y] = p;
        *(f16*)(PW + LSWZ(4*lr + r, 16*y + lc)) = (f16)p;
      }
      ssum[r] += ps;
      // capture running max per tile in registers: lane lc owns jt=lc, 16+lc
      if (jt < 16) { if (lc == jt) mreg0[r] = mnew; }
      else         { if (lc == jt - 16) mreg1[r] = mnew; }
    }
    // transposed P store, direct from registers: attnT[j][i]
    #pragma unroll
    for (int y = 0; y < 4; y++) {
      f16x4 pk = {(f16)pvr[0][y], (f16)pvr[1][y], (f16)pvr[2][y], (f16)pvr[3][y]};
      *(f16x4*)&attnT[((size_t)z * NSEQ + j0 + 16*y + lc) * NSEQ + i0 + 16*w + 4*lr] = pk;
    }
    // out1 PV (PW per-wave, lgkmcnt-ordered)
    {
      f16x8 pa0 = *(const f16x8*)(PW + LSWZ(lc, 8*lr));
      f16x8 pa1 = *(const f16x8*)(PW + LSWZ(lc, 32 + 8*lr));
      __builtin_amdgcn_s_setprio(1);
      #pragma unroll
      for (int nt = 0; nt < 4; nt++) {
        f16x8 vf0 = *(const f16x8*)(VS + LSWZ(16*nt + lc, 8*lr));
        f16x8 vf1 = *(const f16x8*)(VS + LSWZ(16*nt + lc, 32 + 8*lr));
        o1a[nt] = MFMA16(pa0, vf0, o1a[nt]);
        o1a[nt] = MFMA16(pa1, vf1, o1a[nt]);
      }
      __builtin_amdgcn_s_setprio(0);
    }
    __syncthreads();   // s3: all LDS reads done -> restage ok
  }
  // epilogue: reduce s per row; write fac_t (for pv2) and normalized out1
  float invs[4];
  #pragma unroll
  for (int r = 0; r < 4; r++) {
    float s = ssum[r];
    #pragma unroll
    for (int mk = 1; mk <= 8; mk <<= 1) s += __shfl_xor(s, mk);
    invs[r] = 1.f / s;
    int il = 16*w + 4*lr + r;
    float mf = m_run[r];
    #pragma unroll
    for (int jtb = 0; jtb < 2; jtb++) {
      int jt = jtb * 16 + lc;
      float mv = (jtb == 0) ? mreg0[r] : mreg1[r];
      float fv = exp2f(mv - mf) * invs[r];
      fac_t[((size_t)z * 32 + jt) * NSEQ + i0 + il] = fv;
    }
  }
  #pragma unroll
  for (int nt = 0; nt < 4; nt++)
    #pragma unroll
    for (int r = 0; r < 4; r++) {
      int rw = i0 + 16*w + 4*lr + r;
      o1acc[((size_t)b * NSEQ + rw) * 512 + h * 64 + 16*nt + lc] = (f16)(o1a[nt][r] * invs[r]);
    }
}

// ---------------- pv2: out2[j,d] = sum_i attnT[j,i]*fac_t[jt,i]*v1[i,d] ----
// A-fragments straight from global attnT (no LDS); Vs = v1t rows scaled by
// fac_t at staging (swizzled b128, conflict-free).
__global__ __launch_bounds__(256) void pv2_k(const f16* __restrict__ attnT,
    const f16* __restrict__ v1t, const float* __restrict__ fac_t,
    f16* __restrict__ oacc, int bh0)
{
  __shared__ char vsm[8192];   // Vs [64] swizzled rows: [d][k=i]
  int z = blockIdx.y, bh = bh0 + z, b = bh >> 3, h = bh & 7;
  int r0 = blockIdx.x * 64;    // j-block == jt index
  int tid = threadIdx.x, w = tid >> 6, lane = tid & 63;
  int lr = lane >> 4, lc = lane & 15;
  int row = tid >> 2, cv = (tid & 3) * 16;
  const f16* vp = v1t + ((size_t)bh * 64 + row) * NSEQ + cv;
  const float* fp = fac_t + ((size_t)z * 32 + blockIdx.x) * NSEQ + cv;
  const f16* ap = attnT + ((size_t)z * NSEQ + r0 + 16*w + lc) * NSEQ + 8*lr;
  f32x4 acc[4] = {};
  for (int k0 = 0; k0 < NSEQ; k0 += 64) {
    f16x8 v0 = *(const f16x8*)(vp + k0);
    f16x8 v1 = *(const f16x8*)(vp + k0 + 8);
    float4 f0 = *(const float4*)(fp + k0),     f1 = *(const float4*)(fp + k0 + 4);
    float4 f2 = *(const float4*)(fp + k0 + 8), f3 = *(const float4*)(fp + k0 + 12);
    *(f16x8*)(vsm + LSWZ(row, cv))     = scale8(v0, f0, f1);
    *(f16x8*)(vsm + LSWZ(row, cv + 8)) = scale8(v1, f2, f3);
    __syncthreads();
    f16x8 a0 = *(const f16x8*)(ap + k0);
    f16x8 a1 = *(const f16x8*)(ap + k0 + 32);
    #pragma unroll
    for (int nt = 0; nt < 4; nt++) {
      acc[nt] = MFMA16(a0, *(const f16x8*)(vsm + LSWZ(16*nt + lc, 8*lr)), acc[nt]);
      acc[nt] = MFMA16(a1, *(const f16x8*)(vsm + LSWZ(16*nt + lc, 32 + 8*lr)), acc[nt]);
    }
    __syncthreads();
  }
  #pragma unroll
  for (int nt = 0; nt < 4; nt++)
    #pragma unroll
    for (int r = 0; r < 4; r++) {
      int rw = r0 + 16*w + 4*lr + r;
      oacc[((size_t)b * NSEQ + rw) * 512 + h * 64 + 16*nt + lc] = (f16)acc[nt][r];
    }
}

extern "C" void kernel_launch(void* const* d_in, const int* in_sizes, int n_in,
                              void* d_out, int out_size, void* d_ws, size_t ws_size,
                              hipStream_t stream) {
  const float* x1   = (const float*)d_in[0];
  const float* x2   = (const float*)d_in[1];
  const float* Wq   = (const float*)d_in[2];
  const float* Wk   = (const float*)d_in[3];
  const float* Wv1  = (const float*)d_in[4];
  const float* Wv2  = (const float*)d_in[5];
  const float* Wrel = (const float*)d_in[6];
  const float* rpb  = (const float*)d_in[7];
  const float* Wo1  = (const float*)d_in[8];
  const float* bo1  = (const float*)d_in[9];
  const float* Wo2  = (const float*)d_in[10];
  const float* bo2  = (const float*)d_in[11];
  float* out = (float*)d_out;

  char* base = (char*)d_ws;
  size_t off = 0;
  auto alloc = [&](size_t bytes) -> void* {
    void* p = base + off; off += (bytes + 255) & ~(size_t)255; return p;
  };
  float* pos   = (float*)alloc((size_t)NPOS * 192 * 4);
  f16*   relq  = (f16*)  alloc((size_t)NH * NPOS * 64 * 2);
  f16*   qh    = (f16*)  alloc((size_t)16 * NSEQ * 64 * 2);
  f16*   kbh   = (f16*)  alloc((size_t)16 * NSEQ * 64 * 2);
  f16*   v1t   = (f16*)  alloc((size_t)16 * 64 * NSEQ * 2);
  f16*   v2t   = (f16*)  alloc((size_t)16 * 64 * NSEQ * 2);
  f16*   o1acc = (f16*)  alloc((size_t)2 * NSEQ * 512 * 2);
  f16*   o2acc = (f16*)  alloc((size_t)2 * NSEQ * 512 * 2);
  float* fac_t = (float*)alloc((size_t)16 * 32 * NSEQ * 4);
  size_t baseB = off;

  int chunk = 1;
  for (int c = 16; c >= 1; c >>= 1) {
    size_t needB = baseB + (size_t)c * NSEQ * NSEQ * 2;
    if (needB <= ws_size) { chunk = c; break; }
  }
  f16* attnT = (f16*)(base + baseB);

  pos_embed_k<<<(NPOS + 7) / 8, 256, 0, stream>>>(pos);
  relq_k<<<dim3(8, 64), 256, 0, stream>>>(pos, Wrel, relq);
  projx_k<1024, false><<<dim3(16, 64), 256, 0, stream>>>(x1, Wq, Wv1, qh, v1t, nullptr);
  projx_k<512,  true ><<<dim3(16, 64), 256, 0, stream>>>(x2, Wk, Wv2, kbh, v2t, rpb);

  for (int bh0 = 0; bh0 < 16; bh0 += chunk) {
    attn_k<<<dim3(32, chunk), 256, 0, stream>>>(qh, kbh, relq, v2t, attnT, fac_t, o1acc, bh0);
    pv2_k<<<dim3(32, chunk), 256, 0, stream>>>(attnT, v1t, fac_t, o2acc, bh0);
  }

  outproj_k<<<dim3(16, 128), 256, 0, stream>>>(o1acc, o2acc, Wo1, Wo2, bo1, bo2, out);
}